// Round 1
// baseline (1285.431 us; speedup 1.0000x reference)
//
#include <hip/hip_runtime.h>
#include <hip/hip_bf16.h>
#include <stdint.h>

// ---------------------------------------------------------------------------
// GCN encoder: scatter-add (segment_sum) -> relu -> GEMM1(978->2048)+relu ->
// GEMM2(2048->100). bf16 MFMA for both GEMMs (fp32 accumulate).
// ---------------------------------------------------------------------------

typedef unsigned short u16;
typedef __bf16 bf16x8 __attribute__((ext_vector_type(8)));
typedef float f32x4 __attribute__((ext_vector_type(4)));

#define NGENES 978
#define KPAD   1024
#define H1DIM  2048
#define NOUT   100
#define NOUTP  112   // padded to 7 * 16
#define KSPLIT 8

// round-to-nearest-even f32 -> bf16 (no NaN inputs occur here)
__device__ __forceinline__ u16 f2b(float f) {
    unsigned u = __builtin_bit_cast(unsigned, f);
    u = (u + 0x7FFFu + ((u >> 16) & 1u)) >> 16;
    return (u16)u;
}

// async 16B global -> LDS direct copy (wave-uniform base + lane*16 layout)
__device__ __forceinline__ void gl2lds16(const void* g, void* l) {
    __builtin_amdgcn_global_load_lds(
        (const __attribute__((address_space(1))) void*)(uintptr_t)g,
        (__attribute__((address_space(3))) void*)(unsigned)(uintptr_t)l,
        16, 0, 0);
}

// ---------------------------------------------------------------------------
// Detect whether edges buffer is int64 (odd 4-byte words all zero) or int32.
// ---------------------------------------------------------------------------
__global__ void detect_kernel(const unsigned* __restrict__ e, int* __restrict__ flag) {
    if (threadIdx.x == 0) {
        int is64 = 1;
        for (int i = 0; i < 64; ++i) {
            if (e[2 * i + 1] != 0u) { is64 = 0; break; }
        }
        *flag = is64;
    }
}

// ---------------------------------------------------------------------------
// Scatter-add: agg[dst] += x[src] * gcn_w
// ---------------------------------------------------------------------------
__global__ void scatter_kernel(const void* __restrict__ edges, const float* __restrict__ x,
                               const float* __restrict__ gcn_w, float* __restrict__ agg,
                               const int* __restrict__ flag, int E) {
    long long e = (long long)blockIdx.x * 256 + threadIdx.x;
    if (e >= E) return;
    int s, d;
    if (*flag) {
        const long long* e64 = (const long long*)edges;
        s = (int)e64[e];
        d = (int)e64[(long long)E + e];
    } else {
        const int* e32 = (const int*)edges;
        s = e32[e];
        d = e32[(long long)E + e];
    }
    atomicAdd(&agg[d], x[s] * gcn_w[0]);
}

// ---------------------------------------------------------------------------
// Fused bias + relu + bf16 convert, pad K 978 -> 1024 with zeros.
// A[i][k] = bf16(relu(agg[i*978+k] + gcn_b)), k<978 else 0
// ---------------------------------------------------------------------------
__global__ void act_kernel(const float* __restrict__ agg, const float* __restrict__ gcn_b,
                           u16* __restrict__ A) {
    int idx = blockIdx.x * 256 + threadIdx.x;
    int i = idx >> 10;         // KPAD = 1024
    int k = idx & 1023;
    float v = 0.f;
    if (k < NGENES) {
        v = agg[(size_t)i * NGENES + k] + gcn_b[0];
        v = v > 0.f ? v : 0.f;
    }
    A[idx] = f2b(v);
}

// ---------------------------------------------------------------------------
// W1 [978][2048] f32 -> W1T [2048][1024] bf16 (transposed, K zero-padded)
// ---------------------------------------------------------------------------
__global__ void transposeW1(const float* __restrict__ W1, u16* __restrict__ W1T) {
    __shared__ float t[32][33];
    int n0 = blockIdx.x * 32;
    int k0 = blockIdx.y * 32;
    int tx = threadIdx.x, ty = threadIdx.y;
    for (int r = ty; r < 32; r += 8) {
        int k = k0 + r;
        t[r][tx] = (k < NGENES) ? W1[(size_t)k * H1DIM + n0 + tx] : 0.f;
    }
    __syncthreads();
    for (int r = ty; r < 32; r += 8) {
        int n = n0 + r;
        W1T[(size_t)n * KPAD + k0 + tx] = f2b(t[tx][r]);
    }
}

// ---------------------------------------------------------------------------
// W2 [2048][100] f32 -> W2T [112][2048] bf16 (transposed, N zero-padded)
// ---------------------------------------------------------------------------
__global__ void transposeW2(const float* __restrict__ W2, u16* __restrict__ W2T) {
    __shared__ float t[32][33];
    int n0 = blockIdx.x * 32;
    int k0 = blockIdx.y * 32;
    int tx = threadIdx.x, ty = threadIdx.y;
    for (int r = ty; r < 32; r += 8) {
        int k = k0 + r;
        int n = n0 + tx;
        t[r][tx] = (n < NOUT) ? W2[(size_t)k * NOUT + n] : 0.f;
    }
    __syncthreads();
    for (int r = ty; r < 32; r += 8) {
        int n = n0 + r;
        if (n < NOUTP) W2T[(size_t)n * H1DIM + k0 + tx] = f2b(t[tx][r]);
    }
}

// ---------------------------------------------------------------------------
// GEMM1: H[8192][2048] = relu(A[8192][1024] @ W1T^T + b1), bf16 out.
// 128x128 tile, BK=32, 256 threads = 4 waves in 2x2, each wave 64x64
// (4x4 tiles of 16x16x32 MFMA). Both A and B tiles in [row][k] layout
// (B comes pre-transposed) so fragment reads are contiguous ds_read_b128.
// ---------------------------------------------------------------------------
__global__ __launch_bounds__(256) void gemm1_kernel(const u16* __restrict__ A,
                                                    const u16* __restrict__ Bt,
                                                    const float* __restrict__ b1,
                                                    u16* __restrict__ H) {
    __shared__ u16 As[128 * 32];
    __shared__ u16 Bs[128 * 32];
    const int tid = threadIdx.x;
    const int m0 = blockIdx.y * 128;
    const int n0 = blockIdx.x * 128;
    const int wave = tid >> 6;
    const int lane = tid & 63;
    const int wm = (wave >> 1) * 64;
    const int wn = (wave & 1) * 64;
    const int quad = lane >> 4;
    const int l16 = lane & 15;

    f32x4 acc[4][4];
#pragma unroll
    for (int i = 0; i < 4; ++i)
#pragma unroll
        for (int j = 0; j < 4; ++j)
            acc[i][j] = (f32x4){0.f, 0.f, 0.f, 0.f};

    // staging: 512 chunks of 16B per tile, 2 per thread, LDS offset = chunk*16
    const int ch0 = tid, ch1 = tid + 256;
    const u16* ag0 = A + (size_t)(m0 + (ch0 >> 2)) * KPAD + (ch0 & 3) * 8;
    const u16* ag1 = A + (size_t)(m0 + (ch1 >> 2)) * KPAD + (ch1 & 3) * 8;
    const u16* bg0 = Bt + (size_t)(n0 + (ch0 >> 2)) * KPAD + (ch0 & 3) * 8;
    const u16* bg1 = Bt + (size_t)(n0 + (ch1 >> 2)) * KPAD + (ch1 & 3) * 8;
    u16* la0 = &As[ch0 * 8];
    u16* la1 = &As[ch1 * 8];
    u16* lb0 = &Bs[ch0 * 8];
    u16* lb1 = &Bs[ch1 * 8];

    for (int k0 = 0; k0 < KPAD; k0 += 32) {
        gl2lds16(ag0, la0);
        gl2lds16(ag1, la1);
        gl2lds16(bg0, lb0);
        gl2lds16(bg1, lb1);
        ag0 += 32; ag1 += 32; bg0 += 32; bg1 += 32;
        __syncthreads();

        bf16x8 af[4], bfr[4];
#pragma unroll
        for (int i = 0; i < 4; ++i)
            af[i] = *(const bf16x8*)&As[(wm + i * 16 + l16) * 32 + quad * 8];
#pragma unroll
        for (int j = 0; j < 4; ++j)
            bfr[j] = *(const bf16x8*)&Bs[(wn + j * 16 + l16) * 32 + quad * 8];
#pragma unroll
        for (int i = 0; i < 4; ++i)
#pragma unroll
            for (int j = 0; j < 4; ++j)
                acc[i][j] = __builtin_amdgcn_mfma_f32_16x16x32_bf16(af[i], bfr[j], acc[i][j], 0, 0, 0);
        __syncthreads();
    }

    // epilogue: C/D layout col=lane&15, row=quad*4+reg
#pragma unroll
    for (int j = 0; j < 4; ++j) {
        const int col = n0 + wn + j * 16 + l16;
        const float bv = b1[col];
#pragma unroll
        for (int i = 0; i < 4; ++i) {
            const int rbase = m0 + wm + i * 16 + quad * 4;
#pragma unroll
            for (int r = 0; r < 4; ++r) {
                float v = acc[i][j][r] + bv;
                v = v > 0.f ? v : 0.f;
                H[(size_t)(rbase + r) * H1DIM + col] = f2b(v);
            }
        }
    }
}

// ---------------------------------------------------------------------------
// GEMM2: out[8192][100] += H[8192][2048] @ W2T^T + b2, split-K with atomics.
// BM=64 (4 waves x 16 rows), BN=112 (7 MFMA tiles), BK=32, K-chunk=2048/8=256.
// ---------------------------------------------------------------------------
__global__ __launch_bounds__(256) void gemm2_kernel(const u16* __restrict__ Hh,
                                                    const u16* __restrict__ W2T,
                                                    const float* __restrict__ b2,
                                                    float* __restrict__ out) {
    __shared__ u16 As[64 * 32];
    __shared__ u16 Bs[NOUTP * 32];
    const int tid = threadIdx.x;
    const int m0 = blockIdx.y * 64;
    const int kc = blockIdx.x;                   // 0..KSPLIT-1
    const int kbase = kc * (H1DIM / KSPLIT);     // 256-wide K chunk
    const int wave = tid >> 6;
    const int lane = tid & 63;
    const int quad = lane >> 4;
    const int l16 = lane & 15;

    f32x4 acc[7];
#pragma unroll
    for (int j = 0; j < 7; ++j) acc[j] = (f32x4){0.f, 0.f, 0.f, 0.f};

    // A: 64x32 = 256 chunks (1/thread). B: 112x32 = 448 chunks (tid, tid+256<448)
    const u16* ag = Hh + (size_t)(m0 + (tid >> 2)) * H1DIM + kbase + (tid & 3) * 8;
    u16* la = &As[tid * 8];
    const u16* bg0 = W2T + (size_t)(tid >> 2) * H1DIM + kbase + (tid & 3) * 8;
    u16* lb0 = &Bs[tid * 8];
    const int ch1 = tid + 256;
    const u16* bg1 = W2T + (size_t)(ch1 >> 2) * H1DIM + kbase + (ch1 & 3) * 8;
    u16* lb1 = &Bs[ch1 * 8];
    const bool bact = (ch1 < NOUTP * 4);         // waves 0-2 only, wave-uniform

    for (int kk = 0; kk < H1DIM / KSPLIT; kk += 32) {
        gl2lds16(ag, la);
        gl2lds16(bg0, lb0);
        if (bact) gl2lds16(bg1, lb1);
        ag += 32; bg0 += 32; bg1 += 32;
        __syncthreads();

        bf16x8 af = *(const bf16x8*)&As[(wave * 16 + l16) * 32 + quad * 8];
#pragma unroll
        for (int j = 0; j < 7; ++j) {
            bf16x8 bfr = *(const bf16x8*)&Bs[(j * 16 + l16) * 32 + quad * 8];
            acc[j] = __builtin_amdgcn_mfma_f32_16x16x32_bf16(af, bfr, acc[j], 0, 0, 0);
        }
        __syncthreads();
    }

#pragma unroll
    for (int j = 0; j < 7; ++j) {
        const int col = j * 16 + l16;
        if (col < NOUT) {
            const float bv = (kc == 0) ? b2[col] : 0.f;
            const int rbase = m0 + wave * 16 + quad * 4;
#pragma unroll
            for (int r = 0; r < 4; ++r)
                atomicAdd(&out[(size_t)(rbase + r) * NOUT + col], acc[j][r] + bv);
        }
    }
}

// ---------------------------------------------------------------------------
extern "C" void kernel_launch(void* const* d_in, const int* in_sizes, int n_in,
                              void* d_out, int out_size, void* d_ws, size_t ws_size,
                              hipStream_t stream) {
    const float* inputs = (const float*)d_in[0];
    const void*  edges  = d_in[1];
    const float* gcn_w  = (const float*)d_in[2];
    const float* gcn_b  = (const float*)d_in[3];
    const float* W1     = (const float*)d_in[4];
    const float* b1     = (const float*)d_in[5];
    const float* W2     = (const float*)d_in[6];
    const float* b2     = (const float*)d_in[7];
    float* out = (float*)d_out;

    const int N = in_sizes[0];          // 8192 * 978 = 8,011,776
    const int Brows = N / NGENES;       // 8192
    const int E = in_sizes[1] / 2;      // 20,000,000

    // workspace carve-up (256B aligned)
    char* ws = (char*)d_ws;
    size_t off = 0;
    auto carve = [&](size_t bytes) -> void* {
        void* p = ws + off;
        off = (off + bytes + 255) & ~(size_t)255;
        return p;
    };
    float* agg = (float*)carve((size_t)N * 4);
    u16*   Abf = (u16*)carve((size_t)Brows * KPAD * 2);
    u16*   W1T = (u16*)carve((size_t)H1DIM * KPAD * 2);
    u16*   W2Tp = (u16*)carve((size_t)NOUTP * H1DIM * 2);
    u16*   H1  = (u16*)carve((size_t)Brows * H1DIM * 2);
    int*   flag = (int*)carve(256);
    (void)ws_size;

    hipMemsetAsync(agg, 0, (size_t)N * 4, stream);
    hipMemsetAsync(out, 0, (size_t)out_size * 4, stream);

    detect_kernel<<<1, 64, 0, stream>>>((const unsigned*)edges, flag);

    const int sblocks = (E + 255) / 256;
    scatter_kernel<<<sblocks, 256, 0, stream>>>(edges, inputs, gcn_w, agg, flag, E);

    act_kernel<<<(Brows * KPAD) / 256, 256, 0, stream>>>(agg, gcn_b, Abf);

    transposeW1<<<dim3(H1DIM / 32, KPAD / 32), dim3(32, 8), 0, stream>>>(W1, W1T);
    transposeW2<<<dim3(4, H1DIM / 32), dim3(32, 8), 0, stream>>>(W2, W2Tp);

    gemm1_kernel<<<dim3(H1DIM / 128, Brows / 128), 256, 0, stream>>>(Abf, W1T, b1, H1);
    gemm2_kernel<<<dim3(KSPLIT, Brows / 64), 256, 0, stream>>>(H1, W2Tp, b2, out);
}

// Round 2
// 1171.249 us; speedup vs baseline: 1.0975x; 1.0975x over previous
//
#include <hip/hip_runtime.h>
#include <hip/hip_bf16.h>
#include <stdint.h>

// ---------------------------------------------------------------------------
// GCN encoder: binned scatter-add (segment_sum) -> relu -> GEMM1(978->2048)
// + relu -> GEMM2(2048->100). bf16 MFMA for both GEMMs (fp32 accumulate).
//
// Scatter strategy (R2): 20M random atomics over 32MB were line-movement
// bound (1.85GB HBM @ 1.9TB/s = 977us). Replace with deterministic radix
// binning: histogram -> scan -> bucket-grouped packed pairs -> LDS accumulate.
// ---------------------------------------------------------------------------

typedef unsigned short u16;
typedef unsigned int u32;
typedef __bf16 bf16x8 __attribute__((ext_vector_type(8)));
typedef float f32x4 __attribute__((ext_vector_type(4)));

#define NGENES 978
#define KPAD   1024
#define H1DIM  2048
#define NOUT   100
#define NOUTP  112   // padded to 7 * 16
#define KSPLIT 8

// scatter binning: 8,011,776 nodes = 978 buckets x 8192 nodes (exact)
#define NB      978
#define BSH     13
#define BNODES  8192
#define NWG_BIN 1024

// round-to-nearest-even f32 -> bf16
__device__ __forceinline__ u16 f2b(float f) {
    unsigned u = __builtin_bit_cast(unsigned, f);
    u = (u + 0x7FFFu + ((u >> 16) & 1u)) >> 16;
    return (u16)u;
}

// async 16B global -> LDS direct copy (wave-uniform base + lane*16 layout)
__device__ __forceinline__ void gl2lds16(const void* g, void* l) {
    __builtin_amdgcn_global_load_lds(
        (const __attribute__((address_space(1))) void*)(uintptr_t)g,
        (__attribute__((address_space(3))) void*)(unsigned)(uintptr_t)l,
        16, 0, 0);
}

// ---------------------------------------------------------------------------
// Detect whether edges buffer is int64 (odd 4-byte words all zero) or int32.
// ---------------------------------------------------------------------------
__global__ void detect_kernel(const unsigned* __restrict__ e, int* __restrict__ flag) {
    if (threadIdx.x == 0) {
        int is64 = 1;
        for (int i = 0; i < 64; ++i) {
            if (e[2 * i + 1] != 0u) { is64 = 0; break; }
        }
        *flag = is64;
    }
}

// ---------------------------------------------------------------------------
// Binned scatter, kernel A: per-chunk bucket histogram of dst.
// hist layout bucket-major: hist[b * NWG_BIN + wg]
// ---------------------------------------------------------------------------
__global__ __launch_bounds__(256) void hist_kernel(const void* __restrict__ edges,
                                                   const int* __restrict__ flag, int E,
                                                   u32* __restrict__ hist) {
    __shared__ u32 h[NB];
    for (int i = threadIdx.x; i < NB; i += 256) h[i] = 0;
    __syncthreads();
    const int wg = blockIdx.x;
    const int per = (E + NWG_BIN - 1) / NWG_BIN;
    const int s = wg * per;
    const int e = min(E, s + per);
    if (*flag) {
        const uint2* dst64 = (const uint2*)edges + E;   // element i at byte 8*(E+i)
        for (int i = s + threadIdx.x; i < e; i += 256)
            atomicAdd(&h[dst64[i].x >> BSH], 1u);
    } else {
        const u32* dst32 = (const u32*)edges + E;
        for (int i = s + threadIdx.x; i < e; i += 256)
            atomicAdd(&h[dst32[i] >> BSH], 1u);
    }
    __syncthreads();
    for (int b = threadIdx.x; b < NB; b += 256) hist[(size_t)b * NWG_BIN + wg] = h[b];
}

// ---------------------------------------------------------------------------
// Kernel B: per-bucket exclusive scan over the NWG_BIN chunk counts (in place)
// plus per-bucket totals. One wave per bucket.
// ---------------------------------------------------------------------------
__global__ void scan_wg_kernel(u32* __restrict__ hist, u32* __restrict__ totals) {
    const int b = blockIdx.x;
    u32* row = hist + (size_t)b * NWG_BIN;
    const int lane = threadIdx.x;
    u32 running = 0;
#pragma unroll
    for (int it = 0; it < NWG_BIN / 64; ++it) {
        u32 v = row[it * 64 + lane];
        u32 incl = v;
#pragma unroll
        for (int off = 1; off < 64; off <<= 1) {
            u32 t = __shfl_up(incl, off, 64);
            if (lane >= off) incl += t;
        }
        row[it * 64 + lane] = running + incl - v;
        running += __shfl(incl, 63, 64);
    }
    if (lane == 0) totals[b] = running;
}

// ---------------------------------------------------------------------------
// Kernel B2: exclusive scan of NB bucket totals -> bases[0..NB] (bases[NB]=E).
// Single wave.
// ---------------------------------------------------------------------------
__global__ void scan_bucket_kernel(const u32* __restrict__ totals, u32* __restrict__ bases) {
    const int lane = threadIdx.x;
    u32 running = 0;
    const int iters = (NB + 63) / 64;
    for (int it = 0; it < iters; ++it) {
        int idx = it * 64 + lane;
        u32 v = (idx < NB) ? totals[idx] : 0;
        u32 incl = v;
#pragma unroll
        for (int off = 1; off < 64; off <<= 1) {
            u32 t = __shfl_up(incl, off, 64);
            if (lane >= off) incl += t;
        }
        if (idx < NB) bases[idx] = running + incl - v;
        running += __shfl(incl, 63, 64);
    }
    if (lane == 0) bases[NB] = running;
}

// ---------------------------------------------------------------------------
// Kernel C: scatter edges into bucket-grouped packed pairs.
// pair = (dst_local << 16) | bf16(x[src] * gcn_w). LDS per-bucket cursors,
// deterministic offsets from hist/bases -> zero global atomics.
// ---------------------------------------------------------------------------
__global__ __launch_bounds__(256) void binscatter_kernel(const void* __restrict__ edges,
                                                         const float* __restrict__ x,
                                                         const float* __restrict__ gcn_w,
                                                         const int* __restrict__ flag, int E,
                                                         const u32* __restrict__ hist,
                                                         const u32* __restrict__ bases,
                                                         u32* __restrict__ pairs) {
    __shared__ u32 cur[NB];
    const int wg = blockIdx.x;
    for (int b = threadIdx.x; b < NB; b += 256)
        cur[b] = bases[b] + hist[(size_t)b * NWG_BIN + wg];
    __syncthreads();
    const float w = gcn_w[0];
    const int per = (E + NWG_BIN - 1) / NWG_BIN;
    const int s = wg * per;
    const int e = min(E, s + per);
    if (*flag) {
        const uint2* e64 = (const uint2*)edges;
        for (int i = s + threadIdx.x; i < e; i += 256) {
            u32 src = e64[i].x;
            u32 d = e64[(size_t)E + i].x;
            float v = x[src] * w;
            u32 pos = atomicAdd(&cur[d >> BSH], 1u);
            pairs[pos] = ((d & (BNODES - 1)) << 16) | (u32)f2b(v);
        }
    } else {
        const u32* e32 = (const u32*)edges;
        for (int i = s + threadIdx.x; i < e; i += 256) {
            u32 src = e32[i];
            u32 d = e32[(size_t)E + i];
            float v = x[src] * w;
            u32 pos = atomicAdd(&cur[d >> BSH], 1u);
            pairs[pos] = ((d & (BNODES - 1)) << 16) | (u32)f2b(v);
        }
    }
}

// ---------------------------------------------------------------------------
// Kernel D: per-bucket LDS accumulate (32KB fp32 tile), stream pairs, write agg.
// Covers every node -> replaces agg memset.
// ---------------------------------------------------------------------------
__global__ __launch_bounds__(256) void accum_kernel(const u32* __restrict__ pairs,
                                                    const u32* __restrict__ bases,
                                                    float* __restrict__ agg) {
    __shared__ float acc[BNODES];    // 32 KB
    for (int i = threadIdx.x; i < BNODES; i += 256) acc[i] = 0.f;
    __syncthreads();
    const int b = blockIdx.x;
    const u32 p0 = bases[b], p1 = bases[b + 1];
    for (u32 p = p0 + threadIdx.x; p < p1; p += 256) {
        u32 pk = pairs[p];
        float v = __builtin_bit_cast(float, (pk & 0xFFFFu) << 16);   // bf16 -> f32
        atomicAdd(&acc[pk >> 16], v);
    }
    __syncthreads();
    const size_t node0 = (size_t)b << BSH;
    for (int i = threadIdx.x; i < BNODES; i += 256) agg[node0 + i] = acc[i];
}

// ---------------------------------------------------------------------------
// Legacy direct-atomic scatter (fallback if workspace too small).
// ---------------------------------------------------------------------------
__global__ void scatter_kernel(const void* __restrict__ edges, const float* __restrict__ x,
                               const float* __restrict__ gcn_w, float* __restrict__ agg,
                               const int* __restrict__ flag, int E) {
    long long e = (long long)blockIdx.x * 256 + threadIdx.x;
    if (e >= E) return;
    int s, d;
    if (*flag) {
        const long long* e64 = (const long long*)edges;
        s = (int)e64[e];
        d = (int)e64[(long long)E + e];
    } else {
        const int* e32 = (const int*)edges;
        s = e32[e];
        d = e32[(long long)E + e];
    }
    atomicAdd(&agg[d], x[s] * gcn_w[0]);
}

// ---------------------------------------------------------------------------
// Fused bias + relu + bf16 convert, pad K 978 -> 1024 with zeros.
// ---------------------------------------------------------------------------
__global__ void act_kernel(const float* __restrict__ agg, const float* __restrict__ gcn_b,
                           u16* __restrict__ A) {
    int idx = blockIdx.x * 256 + threadIdx.x;
    int i = idx >> 10;         // KPAD = 1024
    int k = idx & 1023;
    float v = 0.f;
    if (k < NGENES) {
        v = agg[(size_t)i * NGENES + k] + gcn_b[0];
        v = v > 0.f ? v : 0.f;
    }
    A[idx] = f2b(v);
}

// ---------------------------------------------------------------------------
// W1 [978][2048] f32 -> W1T [2048][1024] bf16 (transposed, K zero-padded)
// ---------------------------------------------------------------------------
__global__ void transposeW1(const float* __restrict__ W1, u16* __restrict__ W1T) {
    __shared__ float t[32][33];
    int n0 = blockIdx.x * 32;
    int k0 = blockIdx.y * 32;
    int tx = threadIdx.x, ty = threadIdx.y;
    for (int r = ty; r < 32; r += 8) {
        int k = k0 + r;
        t[r][tx] = (k < NGENES) ? W1[(size_t)k * H1DIM + n0 + tx] : 0.f;
    }
    __syncthreads();
    for (int r = ty; r < 32; r += 8) {
        int n = n0 + r;
        W1T[(size_t)n * KPAD + k0 + tx] = f2b(t[tx][r]);
    }
}

// ---------------------------------------------------------------------------
// W2 [2048][100] f32 -> W2T [112][2048] bf16 (transposed, N zero-padded)
// ---------------------------------------------------------------------------
__global__ void transposeW2(const float* __restrict__ W2, u16* __restrict__ W2T) {
    __shared__ float t[32][33];
    int n0 = blockIdx.x * 32;
    int k0 = blockIdx.y * 32;
    int tx = threadIdx.x, ty = threadIdx.y;
    for (int r = ty; r < 32; r += 8) {
        int k = k0 + r;
        int n = n0 + tx;
        t[r][tx] = (n < NOUT) ? W2[(size_t)k * NOUT + n] : 0.f;
    }
    __syncthreads();
    for (int r = ty; r < 32; r += 8) {
        int n = n0 + r;
        if (n < NOUTP) W2T[(size_t)n * H1DIM + k0 + tx] = f2b(t[tx][r]);
    }
}

// ---------------------------------------------------------------------------
// GEMM1: H[8192][2048] = relu(A[8192][1024] @ W1T^T + b1), bf16 out.
// 128x128 tile, BK=32, 4 waves 2x2, 16x16x32 MFMA, global_load_lds width=16.
// ---------------------------------------------------------------------------
__global__ __launch_bounds__(256) void gemm1_kernel(const u16* __restrict__ A,
                                                    const u16* __restrict__ Bt,
                                                    const float* __restrict__ b1,
                                                    u16* __restrict__ H) {
    __shared__ u16 As[128 * 32];
    __shared__ u16 Bs[128 * 32];
    const int tid = threadIdx.x;
    const int m0 = blockIdx.y * 128;
    const int n0 = blockIdx.x * 128;
    const int wave = tid >> 6;
    const int lane = tid & 63;
    const int wm = (wave >> 1) * 64;
    const int wn = (wave & 1) * 64;
    const int quad = lane >> 4;
    const int l16 = lane & 15;

    f32x4 acc[4][4];
#pragma unroll
    for (int i = 0; i < 4; ++i)
#pragma unroll
        for (int j = 0; j < 4; ++j)
            acc[i][j] = (f32x4){0.f, 0.f, 0.f, 0.f};

    const int ch0 = tid, ch1 = tid + 256;
    const u16* ag0 = A + (size_t)(m0 + (ch0 >> 2)) * KPAD + (ch0 & 3) * 8;
    const u16* ag1 = A + (size_t)(m0 + (ch1 >> 2)) * KPAD + (ch1 & 3) * 8;
    const u16* bg0 = Bt + (size_t)(n0 + (ch0 >> 2)) * KPAD + (ch0 & 3) * 8;
    const u16* bg1 = Bt + (size_t)(n0 + (ch1 >> 2)) * KPAD + (ch1 & 3) * 8;
    u16* la0 = &As[ch0 * 8];
    u16* la1 = &As[ch1 * 8];
    u16* lb0 = &Bs[ch0 * 8];
    u16* lb1 = &Bs[ch1 * 8];

    for (int k0 = 0; k0 < KPAD; k0 += 32) {
        gl2lds16(ag0, la0);
        gl2lds16(ag1, la1);
        gl2lds16(bg0, lb0);
        gl2lds16(bg1, lb1);
        ag0 += 32; ag1 += 32; bg0 += 32; bg1 += 32;
        __syncthreads();

        bf16x8 af[4], bfr[4];
#pragma unroll
        for (int i = 0; i < 4; ++i)
            af[i] = *(const bf16x8*)&As[(wm + i * 16 + l16) * 32 + quad * 8];
#pragma unroll
        for (int j = 0; j < 4; ++j)
            bfr[j] = *(const bf16x8*)&Bs[(wn + j * 16 + l16) * 32 + quad * 8];
#pragma unroll
        for (int i = 0; i < 4; ++i)
#pragma unroll
            for (int j = 0; j < 4; ++j)
                acc[i][j] = __builtin_amdgcn_mfma_f32_16x16x32_bf16(af[i], bfr[j], acc[i][j], 0, 0, 0);
        __syncthreads();
    }

#pragma unroll
    for (int j = 0; j < 4; ++j) {
        const int col = n0 + wn + j * 16 + l16;
        const float bv = b1[col];
#pragma unroll
        for (int i = 0; i < 4; ++i) {
            const int rbase = m0 + wm + i * 16 + quad * 4;
#pragma unroll
            for (int r = 0; r < 4; ++r) {
                float v = acc[i][j][r] + bv;
                v = v > 0.f ? v : 0.f;
                H[(size_t)(rbase + r) * H1DIM + col] = f2b(v);
            }
        }
    }
}

// ---------------------------------------------------------------------------
// GEMM2: out[8192][100] += H[8192][2048] @ W2T^T + b2, split-K with atomics.
// ---------------------------------------------------------------------------
__global__ __launch_bounds__(256) void gemm2_kernel(const u16* __restrict__ Hh,
                                                    const u16* __restrict__ W2T,
                                                    const float* __restrict__ b2,
                                                    float* __restrict__ out) {
    __shared__ u16 As[64 * 32];
    __shared__ u16 Bs[NOUTP * 32];
    const int tid = threadIdx.x;
    const int m0 = blockIdx.y * 64;
    const int kc = blockIdx.x;
    const int kbase = kc * (H1DIM / KSPLIT);
    const int wave = tid >> 6;
    const int lane = tid & 63;
    const int quad = lane >> 4;
    const int l16 = lane & 15;

    f32x4 acc[7];
#pragma unroll
    for (int j = 0; j < 7; ++j) acc[j] = (f32x4){0.f, 0.f, 0.f, 0.f};

    const u16* ag = Hh + (size_t)(m0 + (tid >> 2)) * H1DIM + kbase + (tid & 3) * 8;
    u16* la = &As[tid * 8];
    const u16* bg0 = W2T + (size_t)(tid >> 2) * H1DIM + kbase + (tid & 3) * 8;
    u16* lb0 = &Bs[tid * 8];
    const int ch1 = tid + 256;
    const u16* bg1 = W2T + (size_t)(ch1 >> 2) * H1DIM + kbase + (ch1 & 3) * 8;
    u16* lb1 = &Bs[ch1 * 8];
    const bool bact = (ch1 < NOUTP * 4);

    for (int kk = 0; kk < H1DIM / KSPLIT; kk += 32) {
        gl2lds16(ag, la);
        gl2lds16(bg0, lb0);
        if (bact) gl2lds16(bg1, lb1);
        ag += 32; bg0 += 32; bg1 += 32;
        __syncthreads();

        bf16x8 af = *(const bf16x8*)&As[(wave * 16 + l16) * 32 + quad * 8];
#pragma unroll
        for (int j = 0; j < 7; ++j) {
            bf16x8 bfr = *(const bf16x8*)&Bs[(j * 16 + l16) * 32 + quad * 8];
            acc[j] = __builtin_amdgcn_mfma_f32_16x16x32_bf16(af, bfr, acc[j], 0, 0, 0);
        }
        __syncthreads();
    }

#pragma unroll
    for (int j = 0; j < 7; ++j) {
        const int col = j * 16 + l16;
        if (col < NOUT) {
            const float bv = (kc == 0) ? b2[col] : 0.f;
            const int rbase = m0 + wave * 16 + quad * 4;
#pragma unroll
            for (int r = 0; r < 4; ++r)
                atomicAdd(&out[(size_t)(rbase + r) * NOUT + col], acc[j][r] + bv);
        }
    }
}

// ---------------------------------------------------------------------------
extern "C" void kernel_launch(void* const* d_in, const int* in_sizes, int n_in,
                              void* d_out, int out_size, void* d_ws, size_t ws_size,
                              hipStream_t stream) {
    const float* inputs = (const float*)d_in[0];
    const void*  edges  = d_in[1];
    const float* gcn_w  = (const float*)d_in[2];
    const float* gcn_b  = (const float*)d_in[3];
    const float* W1     = (const float*)d_in[4];
    const float* b1     = (const float*)d_in[5];
    const float* W2     = (const float*)d_in[6];
    const float* b2     = (const float*)d_in[7];
    float* out = (float*)d_out;

    const int N = in_sizes[0];          // 8192 * 978 = 8,011,776
    const int Brows = N / NGENES;       // 8192
    const int E = in_sizes[1] / 2;      // 20,000,000

    char* ws = (char*)d_ws;
    size_t off = 0;
    auto carve = [&](size_t bytes) -> void* {
        void* p = ws + off;
        off = (off + bytes + 255) & ~(size_t)255;
        return p;
    };
    float* agg = (float*)carve((size_t)N * 4);
    u16*   Abf = (u16*)carve((size_t)Brows * KPAD * 2);
    u16*   W1T = (u16*)carve((size_t)H1DIM * KPAD * 2);
    u16*   W2Tp = (u16*)carve((size_t)NOUTP * H1DIM * 2);
    u16*   H1  = (u16*)carve((size_t)Brows * H1DIM * 2);
    int*   flag = (int*)carve(256);
    // binned-scatter extras
    u32*   hist   = (u32*)carve((size_t)NB * NWG_BIN * 4);
    u32*   totals = (u32*)carve((size_t)NB * 4);
    u32*   bases  = (u32*)carve((size_t)(NB + 1) * 4);
    u32*   pairs  = (u32*)carve((size_t)E * 4);
    const bool use_binned = (off <= ws_size);

    hipMemsetAsync(out, 0, (size_t)out_size * 4, stream);
    detect_kernel<<<1, 64, 0, stream>>>((const unsigned*)edges, flag);

    if (use_binned) {
        hist_kernel<<<NWG_BIN, 256, 0, stream>>>(edges, flag, E, hist);
        scan_wg_kernel<<<NB, 64, 0, stream>>>(hist, totals);
        scan_bucket_kernel<<<1, 64, 0, stream>>>(totals, bases);
        binscatter_kernel<<<NWG_BIN, 256, 0, stream>>>(edges, inputs, gcn_w, flag, E,
                                                       hist, bases, pairs);
        accum_kernel<<<NB, 256, 0, stream>>>(pairs, bases, agg);
    } else {
        hipMemsetAsync(agg, 0, (size_t)N * 4, stream);
        const int sblocks = (E + 255) / 256;
        scatter_kernel<<<sblocks, 256, 0, stream>>>(edges, inputs, gcn_w, agg, flag, E);
    }

    act_kernel<<<(Brows * KPAD) / 256, 256, 0, stream>>>(agg, gcn_b, Abf);

    transposeW1<<<dim3(H1DIM / 32, KPAD / 32), dim3(32, 8), 0, stream>>>(W1, W1T);
    transposeW2<<<dim3(4, H1DIM / 32), dim3(32, 8), 0, stream>>>(W2, W2Tp);

    gemm1_kernel<<<dim3(H1DIM / 128, Brows / 128), 256, 0, stream>>>(Abf, W1T, b1, H1);
    gemm2_kernel<<<dim3(KSPLIT, Brows / 64), 256, 0, stream>>>(H1, W2Tp, b2, out);
}

// Round 3
// 1021.536 us; speedup vs baseline: 1.2583x; 1.1466x over previous
//
#include <hip/hip_runtime.h>
#include <hip/hip_bf16.h>
#include <stdint.h>

// ---------------------------------------------------------------------------
// GCN encoder: binned scatter-add (segment_sum) -> relu -> GEMM1(978->2048)
// + relu -> GEMM2(2048->100). bf16 MFMA for both GEMMs (fp32 accumulate).
//
// R3: binscatter was latency-bound (0.047 gathers/cyc/CU, MLP~1.8).
// Fix: 8-deep manual load batching, 2048 WGs (100% occupancy), bf16 gather
// table (16MB) replacing fp32 inputs (32MB) in the hot gather.
// ---------------------------------------------------------------------------

typedef unsigned short u16;
typedef unsigned int u32;
typedef __bf16 bf16x8 __attribute__((ext_vector_type(8)));
typedef float f32x4 __attribute__((ext_vector_type(4)));

#define NGENES 978
#define KPAD   1024
#define H1DIM  2048
#define NOUT   100
#define NOUTP  112   // padded to 7 * 16
#define KSPLIT 8

// scatter binning: 8,011,776 nodes = 978 buckets x 8192 nodes (exact)
#define NB      978
#define BSH     13
#define BNODES  8192
#define NWG_BIN 2048

// round-to-nearest-even f32 -> bf16
__device__ __forceinline__ u16 f2b(float f) {
    unsigned u = __builtin_bit_cast(unsigned, f);
    u = (u + 0x7FFFu + ((u >> 16) & 1u)) >> 16;
    return (u16)u;
}

// async 16B global -> LDS direct copy (wave-uniform base + lane*16 layout)
__device__ __forceinline__ void gl2lds16(const void* g, void* l) {
    __builtin_amdgcn_global_load_lds(
        (const __attribute__((address_space(1))) void*)(uintptr_t)g,
        (__attribute__((address_space(3))) void*)(unsigned)(uintptr_t)l,
        16, 0, 0);
}

// ---------------------------------------------------------------------------
// Detect whether edges buffer is int64 (odd 4-byte words all zero) or int32.
// ---------------------------------------------------------------------------
__global__ void detect_kernel(const unsigned* __restrict__ e, int* __restrict__ flag) {
    if (threadIdx.x == 0) {
        int is64 = 1;
        for (int i = 0; i < 64; ++i) {
            if (e[2 * i + 1] != 0u) { is64 = 0; break; }
        }
        *flag = is64;
    }
}

// ---------------------------------------------------------------------------
// xb[n] = bf16(inputs[n] * gcn_w) — the gather table (16 MB instead of 32).
// ---------------------------------------------------------------------------
__global__ void xbf_kernel(const float* __restrict__ x, const float* __restrict__ gcn_w,
                           u16* __restrict__ xb, int N) {
    const float w = gcn_w[0];
    int i = (blockIdx.x * 256 + threadIdx.x) * 4;
    if (i + 3 < N) {
        float4 v = *(const float4*)&x[i];
        xb[i + 0] = f2b(v.x * w);
        xb[i + 1] = f2b(v.y * w);
        xb[i + 2] = f2b(v.z * w);
        xb[i + 3] = f2b(v.w * w);
    } else {
        for (int k = i; k < N; ++k) xb[k] = f2b(x[k] * w);
    }
}

// ---------------------------------------------------------------------------
// Binned scatter, kernel A: per-chunk bucket histogram of dst. 8-deep batched.
// hist layout bucket-major: hist[b * NWG_BIN + wg]
// ---------------------------------------------------------------------------
__global__ __launch_bounds__(256) void hist_kernel(const void* __restrict__ edges,
                                                   const int* __restrict__ flag, int E,
                                                   u32* __restrict__ hist) {
    __shared__ u32 h[NB];
    for (int i = threadIdx.x; i < NB; i += 256) h[i] = 0;
    __syncthreads();
    const int wg = blockIdx.x;
    const int per = (E + NWG_BIN - 1) / NWG_BIN;
    const int s = wg * per;
    const int e = min(E, s + per);
    int i = s + threadIdx.x;
    if (*flag) {
        const uint2* dst64 = (const uint2*)edges + E;
        for (; i + 7 * 256 < e; i += 8 * 256) {
            u32 d[8];
#pragma unroll
            for (int k = 0; k < 8; ++k) d[k] = dst64[i + k * 256].x;
#pragma unroll
            for (int k = 0; k < 8; ++k) atomicAdd(&h[d[k] >> BSH], 1u);
        }
        for (; i < e; i += 256) atomicAdd(&h[dst64[i].x >> BSH], 1u);
    } else {
        const u32* dst32 = (const u32*)edges + E;
        for (; i + 7 * 256 < e; i += 8 * 256) {
            u32 d[8];
#pragma unroll
            for (int k = 0; k < 8; ++k) d[k] = dst32[i + k * 256];
#pragma unroll
            for (int k = 0; k < 8; ++k) atomicAdd(&h[d[k] >> BSH], 1u);
        }
        for (; i < e; i += 256) atomicAdd(&h[dst32[i] >> BSH], 1u);
    }
    __syncthreads();
    for (int b = threadIdx.x; b < NB; b += 256) hist[(size_t)b * NWG_BIN + wg] = h[b];
}

// ---------------------------------------------------------------------------
// Kernel B: per-bucket exclusive scan over the NWG_BIN chunk counts (in place)
// plus per-bucket totals. One wave per bucket.
// ---------------------------------------------------------------------------
__global__ void scan_wg_kernel(u32* __restrict__ hist, u32* __restrict__ totals) {
    const int b = blockIdx.x;
    u32* row = hist + (size_t)b * NWG_BIN;
    const int lane = threadIdx.x;
    u32 running = 0;
#pragma unroll
    for (int it = 0; it < NWG_BIN / 64; ++it) {
        u32 v = row[it * 64 + lane];
        u32 incl = v;
#pragma unroll
        for (int off = 1; off < 64; off <<= 1) {
            u32 t = __shfl_up(incl, off, 64);
            if (lane >= off) incl += t;
        }
        row[it * 64 + lane] = running + incl - v;
        running += __shfl(incl, 63, 64);
    }
    if (lane == 0) totals[b] = running;
}

// ---------------------------------------------------------------------------
// Kernel B2: exclusive scan of NB bucket totals -> bases[0..NB] (bases[NB]=E).
// ---------------------------------------------------------------------------
__global__ void scan_bucket_kernel(const u32* __restrict__ totals, u32* __restrict__ bases) {
    const int lane = threadIdx.x;
    u32 running = 0;
    const int iters = (NB + 63) / 64;
    for (int it = 0; it < iters; ++it) {
        int idx = it * 64 + lane;
        u32 v = (idx < NB) ? totals[idx] : 0;
        u32 incl = v;
#pragma unroll
        for (int off = 1; off < 64; off <<= 1) {
            u32 t = __shfl_up(incl, off, 64);
            if (lane >= off) incl += t;
        }
        if (idx < NB) bases[idx] = running + incl - v;
        running += __shfl(incl, 63, 64);
    }
    if (lane == 0) bases[NB] = running;
}

// ---------------------------------------------------------------------------
// Kernel C: scatter edges into bucket-grouped packed pairs. 8-deep batched.
// pair = (dst_local << 16) | xb[src]. LDS per-bucket cursors, deterministic
// offsets -> zero global atomics.
// ---------------------------------------------------------------------------
__global__ __launch_bounds__(256) void binscatter_kernel(const void* __restrict__ edges,
                                                         const u16* __restrict__ xb,
                                                         const int* __restrict__ flag, int E,
                                                         const u32* __restrict__ hist,
                                                         const u32* __restrict__ bases,
                                                         u32* __restrict__ pairs) {
    __shared__ u32 cur[NB];
    const int wg = blockIdx.x;
    for (int b = threadIdx.x; b < NB; b += 256)
        cur[b] = bases[b] + hist[(size_t)b * NWG_BIN + wg];
    __syncthreads();
    const int per = (E + NWG_BIN - 1) / NWG_BIN;
    const int s = wg * per;
    const int e = min(E, s + per);
    int i = s + threadIdx.x;
    if (*flag) {
        const uint2* e64 = (const uint2*)edges;
        const uint2* d64 = e64 + E;
        for (; i + 7 * 256 < e; i += 8 * 256) {
            u32 src[8], d[8];
            u16 val[8];
#pragma unroll
            for (int k = 0; k < 8; ++k) src[k] = e64[i + k * 256].x;
#pragma unroll
            for (int k = 0; k < 8; ++k) val[k] = xb[src[k]];
#pragma unroll
            for (int k = 0; k < 8; ++k) d[k] = d64[i + k * 256].x;
#pragma unroll
            for (int k = 0; k < 8; ++k) {
                u32 pos = atomicAdd(&cur[d[k] >> BSH], 1u);
                pairs[pos] = ((d[k] & (BNODES - 1)) << 16) | (u32)val[k];
            }
        }
        for (; i < e; i += 256) {
            u32 src = e64[i].x;
            u32 d = d64[i].x;
            u16 v = xb[src];
            u32 pos = atomicAdd(&cur[d >> BSH], 1u);
            pairs[pos] = ((d & (BNODES - 1)) << 16) | (u32)v;
        }
    } else {
        const u32* e32 = (const u32*)edges;
        const u32* d32 = e32 + E;
        for (; i + 7 * 256 < e; i += 8 * 256) {
            u32 src[8], d[8];
            u16 val[8];
#pragma unroll
            for (int k = 0; k < 8; ++k) src[k] = e32[i + k * 256];
#pragma unroll
            for (int k = 0; k < 8; ++k) val[k] = xb[src[k]];
#pragma unroll
            for (int k = 0; k < 8; ++k) d[k] = d32[i + k * 256];
#pragma unroll
            for (int k = 0; k < 8; ++k) {
                u32 pos = atomicAdd(&cur[d[k] >> BSH], 1u);
                pairs[pos] = ((d[k] & (BNODES - 1)) << 16) | (u32)val[k];
            }
        }
        for (; i < e; i += 256) {
            u32 src = e32[i];
            u32 d = d32[i];
            u16 v = xb[src];
            u32 pos = atomicAdd(&cur[d >> BSH], 1u);
            pairs[pos] = ((d & (BNODES - 1)) << 16) | (u32)v;
        }
    }
}

// ---------------------------------------------------------------------------
// Kernel D: per-bucket LDS accumulate (32KB fp32 tile), stream pairs, write agg.
// 512 threads, 4-deep batched pair reads. Covers every node -> replaces memset.
// ---------------------------------------------------------------------------
__global__ __launch_bounds__(512) void accum_kernel(const u32* __restrict__ pairs,
                                                    const u32* __restrict__ bases,
                                                    float* __restrict__ agg) {
    __shared__ float acc[BNODES];    // 32 KB
    for (int i = threadIdx.x; i < BNODES; i += 512) acc[i] = 0.f;
    __syncthreads();
    const int b = blockIdx.x;
    const u32 p0 = bases[b], p1 = bases[b + 1];
    u32 p = p0 + threadIdx.x;
    for (; p + 3 * 512 < p1; p += 4 * 512) {
        u32 pk[4];
#pragma unroll
        for (int k = 0; k < 4; ++k) pk[k] = pairs[p + k * 512];
#pragma unroll
        for (int k = 0; k < 4; ++k) {
            float v = __builtin_bit_cast(float, (pk[k] & 0xFFFFu) << 16);
            atomicAdd(&acc[pk[k] >> 16], v);
        }
    }
    for (; p < p1; p += 512) {
        u32 pk = pairs[p];
        float v = __builtin_bit_cast(float, (pk & 0xFFFFu) << 16);
        atomicAdd(&acc[pk >> 16], v);
    }
    __syncthreads();
    const size_t node0 = (size_t)b << BSH;
    for (int i = threadIdx.x; i < BNODES; i += 512) agg[node0 + i] = acc[i];
}

// ---------------------------------------------------------------------------
// Legacy direct-atomic scatter (fallback if workspace too small).
// ---------------------------------------------------------------------------
__global__ void scatter_kernel(const void* __restrict__ edges, const float* __restrict__ x,
                               const float* __restrict__ gcn_w, float* __restrict__ agg,
                               const int* __restrict__ flag, int E) {
    long long e = (long long)blockIdx.x * 256 + threadIdx.x;
    if (e >= E) return;
    int s, d;
    if (*flag) {
        const long long* e64 = (const long long*)edges;
        s = (int)e64[e];
        d = (int)e64[(long long)E + e];
    } else {
        const int* e32 = (const int*)edges;
        s = e32[e];
        d = e32[(long long)E + e];
    }
    atomicAdd(&agg[d], x[s] * gcn_w[0]);
}

// ---------------------------------------------------------------------------
// Fused bias + relu + bf16 convert, pad K 978 -> 1024 with zeros.
// ---------------------------------------------------------------------------
__global__ void act_kernel(const float* __restrict__ agg, const float* __restrict__ gcn_b,
                           u16* __restrict__ A) {
    int idx = blockIdx.x * 256 + threadIdx.x;
    int i = idx >> 10;         // KPAD = 1024
    int k = idx & 1023;
    float v = 0.f;
    if (k < NGENES) {
        v = agg[(size_t)i * NGENES + k] + gcn_b[0];
        v = v > 0.f ? v : 0.f;
    }
    A[idx] = f2b(v);
}

// ---------------------------------------------------------------------------
// W1 [978][2048] f32 -> W1T [2048][1024] bf16 (transposed, K zero-padded)
// ---------------------------------------------------------------------------
__global__ void transposeW1(const float* __restrict__ W1, u16* __restrict__ W1T) {
    __shared__ float t[32][33];
    int n0 = blockIdx.x * 32;
    int k0 = blockIdx.y * 32;
    int tx = threadIdx.x, ty = threadIdx.y;
    for (int r = ty; r < 32; r += 8) {
        int k = k0 + r;
        t[r][tx] = (k < NGENES) ? W1[(size_t)k * H1DIM + n0 + tx] : 0.f;
    }
    __syncthreads();
    for (int r = ty; r < 32; r += 8) {
        int n = n0 + r;
        W1T[(size_t)n * KPAD + k0 + tx] = f2b(t[tx][r]);
    }
}

// ---------------------------------------------------------------------------
// W2 [2048][100] f32 -> W2T [112][2048] bf16 (transposed, N zero-padded)
// ---------------------------------------------------------------------------
__global__ void transposeW2(const float* __restrict__ W2, u16* __restrict__ W2T) {
    __shared__ float t[32][33];
    int n0 = blockIdx.x * 32;
    int k0 = blockIdx.y * 32;
    int tx = threadIdx.x, ty = threadIdx.y;
    for (int r = ty; r < 32; r += 8) {
        int k = k0 + r;
        int n = n0 + tx;
        t[r][tx] = (n < NOUT) ? W2[(size_t)k * NOUT + n] : 0.f;
    }
    __syncthreads();
    for (int r = ty; r < 32; r += 8) {
        int n = n0 + r;
        if (n < NOUTP) W2T[(size_t)n * H1DIM + k0 + tx] = f2b(t[tx][r]);
    }
}

// ---------------------------------------------------------------------------
// GEMM1: H[8192][2048] = relu(A[8192][1024] @ W1T^T + b1), bf16 out.
// 128x128 tile, BK=32, 4 waves 2x2, 16x16x32 MFMA, global_load_lds width=16.
// ---------------------------------------------------------------------------
__global__ __launch_bounds__(256) void gemm1_kernel(const u16* __restrict__ A,
                                                    const u16* __restrict__ Bt,
                                                    const float* __restrict__ b1,
                                                    u16* __restrict__ H) {
    __shared__ u16 As[128 * 32];
    __shared__ u16 Bs[128 * 32];
    const int tid = threadIdx.x;
    const int m0 = blockIdx.y * 128;
    const int n0 = blockIdx.x * 128;
    const int wave = tid >> 6;
    const int lane = tid & 63;
    const int wm = (wave >> 1) * 64;
    const int wn = (wave & 1) * 64;
    const int quad = lane >> 4;
    const int l16 = lane & 15;

    f32x4 acc[4][4];
#pragma unroll
    for (int i = 0; i < 4; ++i)
#pragma unroll
        for (int j = 0; j < 4; ++j)
            acc[i][j] = (f32x4){0.f, 0.f, 0.f, 0.f};

    const int ch0 = tid, ch1 = tid + 256;
    const u16* ag0 = A + (size_t)(m0 + (ch0 >> 2)) * KPAD + (ch0 & 3) * 8;
    const u16* ag1 = A + (size_t)(m0 + (ch1 >> 2)) * KPAD + (ch1 & 3) * 8;
    const u16* bg0 = Bt + (size_t)(n0 + (ch0 >> 2)) * KPAD + (ch0 & 3) * 8;
    const u16* bg1 = Bt + (size_t)(n0 + (ch1 >> 2)) * KPAD + (ch1 & 3) * 8;
    u16* la0 = &As[ch0 * 8];
    u16* la1 = &As[ch1 * 8];
    u16* lb0 = &Bs[ch0 * 8];
    u16* lb1 = &Bs[ch1 * 8];

    for (int k0 = 0; k0 < KPAD; k0 += 32) {
        gl2lds16(ag0, la0);
        gl2lds16(ag1, la1);
        gl2lds16(bg0, lb0);
        gl2lds16(bg1, lb1);
        ag0 += 32; ag1 += 32; bg0 += 32; bg1 += 32;
        __syncthreads();

        bf16x8 af[4], bfr[4];
#pragma unroll
        for (int i = 0; i < 4; ++i)
            af[i] = *(const bf16x8*)&As[(wm + i * 16 + l16) * 32 + quad * 8];
#pragma unroll
        for (int j = 0; j < 4; ++j)
            bfr[j] = *(const bf16x8*)&Bs[(wn + j * 16 + l16) * 32 + quad * 8];
#pragma unroll
        for (int i = 0; i < 4; ++i)
#pragma unroll
            for (int j = 0; j < 4; ++j)
                acc[i][j] = __builtin_amdgcn_mfma_f32_16x16x32_bf16(af[i], bfr[j], acc[i][j], 0, 0, 0);
        __syncthreads();
    }

#pragma unroll
    for (int j = 0; j < 4; ++j) {
        const int col = n0 + wn + j * 16 + l16;
        const float bv = b1[col];
#pragma unroll
        for (int i = 0; i < 4; ++i) {
            const int rbase = m0 + wm + i * 16 + quad * 4;
#pragma unroll
            for (int r = 0; r < 4; ++r) {
                float v = acc[i][j][r] + bv;
                v = v > 0.f ? v : 0.f;
                H[(size_t)(rbase + r) * H1DIM + col] = f2b(v);
            }
        }
    }
}

// ---------------------------------------------------------------------------
// GEMM2: out[8192][100] += H[8192][2048] @ W2T^T + b2, split-K with atomics.
// ---------------------------------------------------------------------------
__global__ __launch_bounds__(256) void gemm2_kernel(const u16* __restrict__ Hh,
                                                    const u16* __restrict__ W2T,
                                                    const float* __restrict__ b2,
                                                    float* __restrict__ out) {
    __shared__ u16 As[64 * 32];
    __shared__ u16 Bs[NOUTP * 32];
    const int tid = threadIdx.x;
    const int m0 = blockIdx.y * 64;
    const int kc = blockIdx.x;
    const int kbase = kc * (H1DIM / KSPLIT);
    const int wave = tid >> 6;
    const int lane = tid & 63;
    const int quad = lane >> 4;
    const int l16 = lane & 15;

    f32x4 acc[7];
#pragma unroll
    for (int j = 0; j < 7; ++j) acc[j] = (f32x4){0.f, 0.f, 0.f, 0.f};

    const u16* ag = Hh + (size_t)(m0 + (tid >> 2)) * H1DIM + kbase + (tid & 3) * 8;
    u16* la = &As[tid * 8];
    const u16* bg0 = W2T + (size_t)(tid >> 2) * H1DIM + kbase + (tid & 3) * 8;
    u16* lb0 = &Bs[tid * 8];
    const int ch1 = tid + 256;
    const u16* bg1 = W2T + (size_t)(ch1 >> 2) * H1DIM + kbase + (ch1 & 3) * 8;
    u16* lb1 = &Bs[ch1 * 8];
    const bool bact = (ch1 < NOUTP * 4);

    for (int kk = 0; kk < H1DIM / KSPLIT; kk += 32) {
        gl2lds16(ag, la);
        gl2lds16(bg0, lb0);
        if (bact) gl2lds16(bg1, lb1);
        ag += 32; bg0 += 32; bg1 += 32;
        __syncthreads();

        bf16x8 af = *(const bf16x8*)&As[(wave * 16 + l16) * 32 + quad * 8];
#pragma unroll
        for (int j = 0; j < 7; ++j) {
            bf16x8 bfr = *(const bf16x8*)&Bs[(j * 16 + l16) * 32 + quad * 8];
            acc[j] = __builtin_amdgcn_mfma_f32_16x16x32_bf16(af, bfr, acc[j], 0, 0, 0);
        }
        __syncthreads();
    }

#pragma unroll
    for (int j = 0; j < 7; ++j) {
        const int col = j * 16 + l16;
        if (col < NOUT) {
            const float bv = (kc == 0) ? b2[col] : 0.f;
            const int rbase = m0 + wave * 16 + quad * 4;
#pragma unroll
            for (int r = 0; r < 4; ++r)
                atomicAdd(&out[(size_t)(rbase + r) * NOUT + col], acc[j][r] + bv);
        }
    }
}

// ---------------------------------------------------------------------------
extern "C" void kernel_launch(void* const* d_in, const int* in_sizes, int n_in,
                              void* d_out, int out_size, void* d_ws, size_t ws_size,
                              hipStream_t stream) {
    const float* inputs = (const float*)d_in[0];
    const void*  edges  = d_in[1];
    const float* gcn_w  = (const float*)d_in[2];
    const float* gcn_b  = (const float*)d_in[3];
    const float* W1     = (const float*)d_in[4];
    const float* b1     = (const float*)d_in[5];
    const float* W2     = (const float*)d_in[6];
    const float* b2     = (const float*)d_in[7];
    float* out = (float*)d_out;

    const int N = in_sizes[0];          // 8192 * 978 = 8,011,776
    const int Brows = N / NGENES;       // 8192
    const int E = in_sizes[1] / 2;      // 20,000,000

    char* ws = (char*)d_ws;
    size_t off = 0;
    auto carve = [&](size_t bytes) -> void* {
        void* p = ws + off;
        off = (off + bytes + 255) & ~(size_t)255;
        return p;
    };
    float* agg = (float*)carve((size_t)N * 4);
    u16*   Abf = (u16*)carve((size_t)Brows * KPAD * 2);
    u16*   W1T = (u16*)carve((size_t)H1DIM * KPAD * 2);
    u16*   W2Tp = (u16*)carve((size_t)NOUTP * H1DIM * 2);
    u16*   H1  = (u16*)carve((size_t)Brows * H1DIM * 2);
    int*   flag = (int*)carve(256);
    // binned-scatter extras
    u16*   xb     = (u16*)carve((size_t)N * 2);
    u32*   hist   = (u32*)carve((size_t)NB * NWG_BIN * 4);
    u32*   totals = (u32*)carve((size_t)NB * 4);
    u32*   bases  = (u32*)carve((size_t)(NB + 1) * 4);
    u32*   pairs  = (u32*)carve((size_t)E * 4);
    const bool use_binned = (off <= ws_size);

    hipMemsetAsync(out, 0, (size_t)out_size * 4, stream);
    detect_kernel<<<1, 64, 0, stream>>>((const unsigned*)edges, flag);

    if (use_binned) {
        xbf_kernel<<<(N / 4 + 255) / 256, 256, 0, stream>>>(inputs, gcn_w, xb, N);
        hist_kernel<<<NWG_BIN, 256, 0, stream>>>(edges, flag, E, hist);
        scan_wg_kernel<<<NB, 64, 0, stream>>>(hist, totals);
        scan_bucket_kernel<<<1, 64, 0, stream>>>(totals, bases);
        binscatter_kernel<<<NWG_BIN, 256, 0, stream>>>(edges, xb, flag, E,
                                                       hist, bases, pairs);
        accum_kernel<<<NB, 512, 0, stream>>>(pairs, bases, agg);
    } else {
        hipMemsetAsync(agg, 0, (size_t)N * 4, stream);
        const int sblocks = (E + 255) / 256;
        scatter_kernel<<<sblocks, 256, 0, stream>>>(edges, inputs, gcn_w, agg, flag, E);
    }

    act_kernel<<<(Brows * KPAD) / 256, 256, 0, stream>>>(agg, gcn_b, Abf);

    transposeW1<<<dim3(H1DIM / 32, KPAD / 32), dim3(32, 8), 0, stream>>>(W1, W1T);
    transposeW2<<<dim3(4, H1DIM / 32), dim3(32, 8), 0, stream>>>(W2, W2Tp);

    gemm1_kernel<<<dim3(H1DIM / 128, Brows / 128), 256, 0, stream>>>(Abf, W1T, b1, H1);
    gemm2_kernel<<<dim3(KSPLIT, Brows / 64), 256, 0, stream>>>(H1, W2Tp, b2, out);
}